// Round 1
// baseline (551.458 us; speedup 1.0000x reference)
//
#include <hip/hip_runtime.h>
#include <hip/hip_fp16.h>

typedef _Float16 f16x8 __attribute__((ext_vector_type(8)));
typedef float f32x4 __attribute__((ext_vector_type(4)));
typedef float float4v __attribute__((ext_vector_type(4)));

#define NPTS_D 64
#define NPTS_H 128

// ---------------------------------------------------------------------------
// Kernel A: y = x @ W1top   (N x 128),  base = x @ (W1bot - W1top) + b1
// thread = one output column c in [0,256); c<128 -> y, c>=128 -> base
// x rows read via uniform (scalar) loads; W column held in 64 VGPRs.
// ---------------------------------------------------------------------------
__global__ __launch_bounds__(256) void precompute_kernel(
    const float* __restrict__ x, const float* __restrict__ W1,
    const float* __restrict__ b1, float* __restrict__ y,
    float* __restrict__ base, int npts)
{
    const int c = threadIdx.x;
    float w[64];
    float bias = 0.0f;
    if (c < 128) {
#pragma unroll
        for (int f = 0; f < 64; ++f) w[f] = W1[f * 128 + c];
    } else {
        const int cc = c - 128;
#pragma unroll
        for (int f = 0; f < 64; ++f)
            w[f] = W1[(64 + f) * 128 + cc] - W1[f * 128 + cc];
        bias = b1[cc];
    }
    for (int n = blockIdx.x; n < npts; n += gridDim.x) {
        const float* xr = x + (size_t)n * 64;   // uniform address -> s_load
        float acc = bias;
#pragma unroll
        for (int f = 0; f < 64; ++f) acc = fmaf(xr[f], w[f], acc);
        if (c < 128) y[(size_t)n * 128 + c] = acc;
        else         base[(size_t)n * 128 + (c - 128)] = acc;
    }
}

// ---------------------------------------------------------------------------
// Kernel B: pack W2 into MFMA B-fragment layout (fp16 hi + lo).
// Fragment fid = ntile*4 + kstep. Lane l, elem e holds
//   W2[k][col], k = kstep*32 + (l>>4)*8 + e, col = ntile*16 + (l&15)
// grid = 32 blocks (one per fid) x 64 threads (one per lane).
// ---------------------------------------------------------------------------
__global__ void pack_w2_kernel(const float* __restrict__ W2,
                               _Float16* __restrict__ whi,
                               _Float16* __restrict__ wlo)
{
    const int fid = blockIdx.x;         // 0..31
    const int nt = fid >> 2, ks = fid & 3;
    const int l = threadIdx.x;          // 0..63
    const int col = nt * 16 + (l & 15);
    const int k0 = ks * 32 + (l >> 4) * 8;
#pragma unroll
    for (int e = 0; e < 8; ++e) {
        float v = W2[(k0 + e) * 128 + col];
        _Float16 hi = (_Float16)v;
        _Float16 lo = (_Float16)(v - (float)hi);
        whi[fid * 512 + l * 8 + e] = hi;
        wlo[fid * 512 + l * 8 + e] = lo;
    }
}

// ---------------------------------------------------------------------------
// Kernel C: main. Block = 256 threads = 4 waves, each wave owns one point.
// Per point: gather y rows of the 16 neighbors directly into A-fragments
// (fp16 hi/lo), then 8 ntiles x (4+4+4) mfma_f32_16x16x32_f16 against the
// LDS-resident packed W2, max-reduce over D rows (= neighbors), coalesced
// 128-float store. W2 (64 KiB) loaded to LDS once per block; no per-point
// barriers.
// ---------------------------------------------------------------------------
__global__ __launch_bounds__(256) void edgeconv_main_kernel(
    const float* __restrict__ y, const float* __restrict__ base,
    const _Float16* __restrict__ whi_g, const _Float16* __restrict__ wlo_g,
    const int* __restrict__ ind, const float* __restrict__ b2,
    float* __restrict__ out, int npts)
{
    __shared__ __align__(16) _Float16 w2_lds[32768];   // 64 KiB: [hi | lo]

    const int tid = threadIdx.x;
    {   // cooperative 64 KiB copy (whi and wlo are contiguous in ws)
        const float4v* src = (const float4v*)whi_g;
        float4v* dst = (float4v*)w2_lds;
        for (int i = tid; i < 4096; i += 256) dst[i] = src[i];
    }
    __syncthreads();

    const int wave = tid >> 6;
    const int lane = tid & 63;
    const int lrow = lane & 15;     // A row / D col index
    const int lkg  = lane >> 4;     // k-group (0..3)

    const f16x8* HI = (const f16x8*)w2_lds;          // 2048 frags-of-lane
    const f16x8* LO = HI + 2048;

    const float b2a = b2[lane];
    const float b2b = b2[lane + 64];

    for (int n = blockIdx.x * 4 + wave; n < npts; n += gridDim.x * 4) {
        const int j = ind[n * 16 + lrow];            // neighbor row

        // ---- build A fragments (hi/lo) straight from global gather ----
        f16x8 a_hi[4], a_lo[4];
#pragma unroll
        for (int ks = 0; ks < 4; ++ks) {
            const int c0 = ks * 32 + lkg * 8;
            const float4v* yp = (const float4v*)(y + (size_t)j * 128 + c0);
            const float4v* bp = (const float4v*)(base + (size_t)n * 128 + c0);
            float4v v0 = yp[0], v1 = yp[1];
            float4v g0 = bp[0], g1 = bp[1];
            float h[8];
#pragma unroll
            for (int e = 0; e < 4; ++e) {
                h[e]     = fmaxf(v0[e] + g0[e], 0.0f);
                h[e + 4] = fmaxf(v1[e] + g1[e], 0.0f);
            }
#pragma unroll
            for (int e = 0; e < 8; ++e) {
                _Float16 hi = (_Float16)h[e];
                a_hi[ks][e] = hi;
                a_lo[ks][e] = (_Float16)(h[e] - (float)hi);
            }
        }

        // ---- 8 ntiles: 12 MFMAs each (hi*Whi, lo*Whi, hi*Wlo) ----
        float mv[8];
#pragma unroll
        for (int nt = 0; nt < 8; ++nt) {
            f16x8 bh[4], bl[4];
#pragma unroll
            for (int ks = 0; ks < 4; ++ks) bh[ks] = HI[(nt * 4 + ks) * 64 + lane];
#pragma unroll
            for (int ks = 0; ks < 4; ++ks) bl[ks] = LO[(nt * 4 + ks) * 64 + lane];

            f32x4 acc0 = {0.f, 0.f, 0.f, 0.f};
            f32x4 acc1 = {0.f, 0.f, 0.f, 0.f};
            f32x4 acc2 = {0.f, 0.f, 0.f, 0.f};
#pragma unroll
            for (int ks = 0; ks < 4; ++ks)
                acc0 = __builtin_amdgcn_mfma_f32_16x16x32_f16(a_hi[ks], bh[ks], acc0, 0, 0, 0);
#pragma unroll
            for (int ks = 0; ks < 4; ++ks)
                acc1 = __builtin_amdgcn_mfma_f32_16x16x32_f16(a_lo[ks], bh[ks], acc1, 0, 0, 0);
#pragma unroll
            for (int ks = 0; ks < 4; ++ks)
                acc2 = __builtin_amdgcn_mfma_f32_16x16x32_f16(a_hi[ks], bl[ks], acc2, 0, 0, 0);

            // rows held by this lane: (lane>>4)*4 + i  -> partial max, then
            // combine the 4 lane-groups holding the other rows of this col.
            float m = fmaxf(fmaxf(acc0[0] + acc1[0] + acc2[0],
                                  acc0[1] + acc1[1] + acc2[1]),
                            fmaxf(acc0[2] + acc1[2] + acc2[2],
                                  acc0[3] + acc1[3] + acc2[3]));
            m = fmaxf(m, __shfl_xor(m, 16));
            m = fmaxf(m, __shfl_xor(m, 32));
            mv[nt] = m;   // every lane now has col-max for col = lane&15
        }

        // ---- coalesced store: lane l writes channels l and l+64 ----
        // channel l       -> ntile = l>>4  (since l == (l>>4)*16 + (l&15))
        // channel l + 64  -> ntile = 4 + (l>>4)
        const int g = lkg;
        float mlo = (g == 0) ? mv[0] : (g == 1) ? mv[1] : (g == 2) ? mv[2] : mv[3];
        float mhi = (g == 0) ? mv[4] : (g == 1) ? mv[5] : (g == 2) ? mv[6] : mv[7];
        out[(size_t)n * 128 + lane]      = mlo + b2a;
        out[(size_t)n * 128 + 64 + lane] = mhi + b2b;
    }
}

// ---------------------------------------------------------------------------
extern "C" void kernel_launch(void* const* d_in, const int* in_sizes, int n_in,
                              void* d_out, int out_size, void* d_ws, size_t ws_size,
                              hipStream_t stream)
{
    const float* x  = (const float*)d_in[0];
    const int*   ind = (const int*)d_in[1];
    const float* W1 = (const float*)d_in[2];
    const float* b1 = (const float*)d_in[3];
    const float* W2 = (const float*)d_in[4];
    const float* b2 = (const float*)d_in[5];
    float* out = (float*)d_out;

    const int npts = in_sizes[0] / 64;           // N = 100000

    // workspace layout (bytes)
    char* ws = (char*)d_ws;
    float* y    = (float*)ws;                                    // N*128 f32
    float* base = (float*)(ws + (size_t)npts * 128 * 4);         // N*128 f32
    _Float16* whi = (_Float16*)(ws + (size_t)npts * 256 * 4);    // 16384 f16
    _Float16* wlo = whi + 16384;                                 // 16384 f16

    hipLaunchKernelGGL(precompute_kernel, dim3(2048), dim3(256), 0, stream,
                       x, W1, b1, y, base, npts);
    hipLaunchKernelGGL(pack_w2_kernel, dim3(32), dim3(64), 0, stream,
                       W2, whi, wlo);
    hipLaunchKernelGGL(edgeconv_main_kernel, dim3(2048), dim3(256), 0, stream,
                       y, base, whi, wlo, ind, b2, out, npts);
}

// Round 3
// 536.325 us; speedup vs baseline: 1.0282x; 1.0282x over previous
//
#include <hip/hip_runtime.h>
#include <hip/hip_fp16.h>

typedef _Float16 f16x8 __attribute__((ext_vector_type(8)));
typedef float f32x4 __attribute__((ext_vector_type(4)));
typedef float float4v __attribute__((ext_vector_type(4)));

// ---------------------------------------------------------------------------
// Kernel A: y = x @ W1top   (N x 128),  base = x @ (W1bot - W1top) + b1
// Block handles 16 rows of x, staged through LDS (coalesced float4 loads).
// Thread c<128 computes y col c, c>=128 computes base col c-128.
// ---------------------------------------------------------------------------
__global__ __launch_bounds__(256) void precompute_kernel(
    const float* __restrict__ x, const float* __restrict__ W1,
    const float* __restrict__ b1, float* __restrict__ y,
    float* __restrict__ base, int npts)
{
    __shared__ float xs[16][64];
    const int tid = threadIdx.x;
    const int c = tid;
    float w[64];
    float bias = 0.0f;
    if (c < 128) {
#pragma unroll
        for (int f = 0; f < 64; ++f) w[f] = W1[f * 128 + c];
    } else {
        const int cc = c - 128;
#pragma unroll
        for (int f = 0; f < 64; ++f)
            w[f] = W1[(64 + f) * 128 + cc] - W1[f * 128 + cc];
        bias = b1[cc];
    }
    const int r0 = blockIdx.x * 16;
    {   // coalesced stage of 16 x-rows: thread -> (row, quad)
        const int r = tid >> 4, q = tid & 15;
        if (r0 + r < npts) {
            float4v v = *(const float4v*)(x + (size_t)(r0 + r) * 64 + q * 4);
            *(float4v*)&xs[r][q * 4] = v;
        }
    }
    __syncthreads();
#pragma unroll 1
    for (int r = 0; r < 16; ++r) {
        const int n = r0 + r;
        if (n >= npts) break;
        float acc = bias;
#pragma unroll
        for (int f = 0; f < 64; ++f) acc = fmaf(xs[r][f], w[f], acc);
        if (c < 128) y[(size_t)n * 128 + c] = acc;
        else         base[(size_t)n * 128 + (c - 128)] = acc;
    }
}

// ---------------------------------------------------------------------------
// Kernel B: pack W2 (fp16 hi only) into MFMA B-fragment layout.
// Fragment fid = ntile*4 + kstep. Lane l, elem e holds
//   W2[k][col], k = kstep*32 + (l>>4)*8 + e, col = ntile*16 + (l&15)
// (mapping verified by round-1 pass)
// ---------------------------------------------------------------------------
__global__ void pack_w2_kernel(const float* __restrict__ W2,
                               _Float16* __restrict__ whi)
{
    const int fid = blockIdx.x;         // 0..31
    const int nt = fid >> 2, ks = fid & 3;
    const int l = threadIdx.x;          // 0..63
    const int col = nt * 16 + (l & 15);
    const int k0 = ks * 32 + (l >> 4) * 8;
#pragma unroll
    for (int e = 0; e < 8; ++e)
        whi[fid * 512 + l * 8 + e] = (_Float16)W2[(k0 + e) * 128 + col];
}

// ---------------------------------------------------------------------------
// Kernel C: main. Block = 256 threads = 4 waves, each wave owns one point per
// grid-stride iteration. 2-product fp16 scheme: (a_hi + a_lo) x W2_hi.
// W2_hi (32 KiB) in LDS; __launch_bounds__(256,4) caps VGPR<=128 so 4 blocks
// (16 waves) fit per CU. ind prefetched one iteration ahead.
// ---------------------------------------------------------------------------
__global__ __launch_bounds__(256, 4) void edgeconv_main_kernel(
    const float* __restrict__ y, const float* __restrict__ base,
    const _Float16* __restrict__ whi_g, const int* __restrict__ ind,
    const float* __restrict__ b2, float* __restrict__ out, int npts)
{
    __shared__ __align__(16) _Float16 w2_lds[16384];   // 32 KiB

    const int tid = threadIdx.x;
    {   // cooperative 32 KiB copy
        const float4v* src = (const float4v*)whi_g;
        float4v* dst = (float4v*)w2_lds;
        for (int i = tid; i < 2048; i += 256) dst[i] = src[i];
    }
    __syncthreads();

    const int wave = tid >> 6;
    const int lane = tid & 63;
    const int lrow = lane & 15;     // A row / D col index
    const int lkg  = lane >> 4;     // k-group (0..3)

    const f16x8* HI = (const f16x8*)w2_lds;

    const float b2a = b2[lane];
    const float b2b = b2[lane + 64];

    const int stride = gridDim.x * 4;
    int n = blockIdx.x * 4 + wave;
    if (n < npts) {
        int j = ind[n * 16 + lrow];             // current neighbor row
        for (; n < npts; n += stride) {
            const int n2 = n + stride;
            int j2 = 0;
            if (n2 < npts) j2 = ind[n2 * 16 + lrow];   // prefetch next ind

            // ---- gather + relu + fp16 hi/lo split into A fragments ----
            f16x8 a_hi[4], a_lo[4];
#pragma unroll
            for (int ks = 0; ks < 4; ++ks) {
                const int c0 = ks * 32 + lkg * 8;
                const float4v* yp = (const float4v*)(y + (size_t)j * 128 + c0);
                const float4v* bp = (const float4v*)(base + (size_t)n * 128 + c0);
                float4v v0 = yp[0], v1 = yp[1];
                float4v g0 = bp[0], g1 = bp[1];
#pragma unroll
                for (int e = 0; e < 4; ++e) {
                    float h0 = fmaxf(v0[e] + g0[e], 0.0f);
                    float h1 = fmaxf(v1[e] + g1[e], 0.0f);
                    _Float16 p0 = (_Float16)h0;
                    _Float16 p1 = (_Float16)h1;
                    a_hi[ks][e]     = p0;
                    a_hi[ks][e + 4] = p1;
                    a_lo[ks][e]     = (_Float16)(h0 - (float)p0);
                    a_lo[ks][e + 4] = (_Float16)(h1 - (float)p1);
                }
            }

            // ---- 8 ntiles: 8 MFMAs each (hi*Whi, lo*Whi) ----
            float mv[8];
#pragma unroll
            for (int nt = 0; nt < 8; ++nt) {
                f16x8 bh[4];
#pragma unroll
                for (int ks = 0; ks < 4; ++ks) bh[ks] = HI[(nt * 4 + ks) * 64 + lane];

                f32x4 acc0 = {0.f, 0.f, 0.f, 0.f};
                f32x4 acc1 = {0.f, 0.f, 0.f, 0.f};
#pragma unroll
                for (int ks = 0; ks < 4; ++ks) {
                    acc0 = __builtin_amdgcn_mfma_f32_16x16x32_f16(a_hi[ks], bh[ks], acc0, 0, 0, 0);
                    acc1 = __builtin_amdgcn_mfma_f32_16x16x32_f16(a_lo[ks], bh[ks], acc1, 0, 0, 0);
                }

                float s0 = acc0[0] + acc1[0];
                float s1 = acc0[1] + acc1[1];
                float s2 = acc0[2] + acc1[2];
                float s3 = acc0[3] + acc1[3];
                float m = fmaxf(fmaxf(s0, s1), fmaxf(s2, s3));
                m = fmaxf(m, __shfl_xor(m, 16));
                m = fmaxf(m, __shfl_xor(m, 32));
                mv[nt] = m;   // col-max for col = lane&15 of ntile nt
            }

            // ---- coalesced store: lane l writes channels l and l+64 ----
            const int g = lkg;
            float mlo = (g == 0) ? mv[0] : (g == 1) ? mv[1] : (g == 2) ? mv[2] : mv[3];
            float mhi = (g == 0) ? mv[4] : (g == 1) ? mv[5] : (g == 2) ? mv[6] : mv[7];
            out[(size_t)n * 128 + lane]      = mlo + b2a;
            out[(size_t)n * 128 + 64 + lane] = mhi + b2b;

            j = j2;
        }
    }
}

// ---------------------------------------------------------------------------
extern "C" void kernel_launch(void* const* d_in, const int* in_sizes, int n_in,
                              void* d_out, int out_size, void* d_ws, size_t ws_size,
                              hipStream_t stream)
{
    const float* x  = (const float*)d_in[0];
    const int*   ind = (const int*)d_in[1];
    const float* W1 = (const float*)d_in[2];
    const float* b1 = (const float*)d_in[3];
    const float* W2 = (const float*)d_in[4];
    const float* b2 = (const float*)d_in[5];
    float* out = (float*)d_out;

    const int npts = in_sizes[0] / 64;           // N = 100000

    // workspace layout (bytes)
    char* ws = (char*)d_ws;
    float* y    = (float*)ws;                                    // N*128 f32
    float* base = (float*)(ws + (size_t)npts * 128 * 4);         // N*128 f32
    _Float16* whi = (_Float16*)(ws + (size_t)npts * 256 * 4);    // 16384 f16

    hipLaunchKernelGGL(precompute_kernel, dim3((npts + 15) / 16), dim3(256), 0, stream,
                       x, W1, b1, y, base, npts);
    hipLaunchKernelGGL(pack_w2_kernel, dim3(32), dim3(64), 0, stream,
                       W2, whi);
    hipLaunchKernelGGL(edgeconv_main_kernel, dim3(2048), dim3(256), 0, stream,
                       y, base, whi, ind, b2, out, npts);
}

// Round 7
// 417.891 us; speedup vs baseline: 1.3196x; 1.2834x over previous
//
#include <hip/hip_runtime.h>
#include <hip/hip_fp16.h>

typedef _Float16 f16x8 __attribute__((ext_vector_type(8)));
typedef float f32x4 __attribute__((ext_vector_type(4)));
typedef float float4v __attribute__((ext_vector_type(4)));

static __device__ __forceinline__ f16x8 relu_add(f16x8 u, f16x8 v) {
    f16x8 s = u + v;
#pragma unroll
    for (int e = 0; e < 8; ++e) s[e] = s[e] > (_Float16)0 ? s[e] : (_Float16)0;
    return s;
}

// ---------------------------------------------------------------------------
// Pack kernel: 64 blocks x 64 lanes.
//  blocks 0..31 : W2 -> whi fragments   (fid = nt*4+ks, nt<8, ks<4, K=128)
//  blocks 32..63: W1 -> wcat fragments  (fid = nt*2+ks, nt<16, ks<2, K=64)
//     wcat cols 0..127  = W1top (y path)
//     wcat cols 128..255 = W1bot - W1top (base path)
// Fragment element (lane l, elem e): B[k0+e][col], col = nt*16+(l&15),
// k0 = ks*32 + (l>>4)*8   (mapping HW-verified in rounds 1/3)
// ---------------------------------------------------------------------------
__global__ void pack_kernel(const float* __restrict__ W1,
                            const float* __restrict__ W2,
                            _Float16* __restrict__ whi,
                            _Float16* __restrict__ wcat)
{
    const int b = blockIdx.x;
    const int l = threadIdx.x;
    if (b < 32) {
        const int nt = b >> 2, ks = b & 3;
        const int col = nt * 16 + (l & 15);
        const int k0 = ks * 32 + (l >> 4) * 8;
#pragma unroll
        for (int e = 0; e < 8; ++e)
            whi[b * 512 + l * 8 + e] = (_Float16)W2[(k0 + e) * 128 + col];
    } else {
        const int fid = b - 32;
        const int nt = fid >> 1, ks = fid & 1;
        const int col = nt * 16 + (l & 15);
        const int k0 = ks * 32 + (l >> 4) * 8;
#pragma unroll
        for (int e = 0; e < 8; ++e) {
            const int k = k0 + e;
            float v;
            if (col < 128) v = W1[k * 128 + col];
            else           v = W1[(64 + k) * 128 + (col - 128)] - W1[k * 128 + (col - 128)];
            wcat[fid * 512 + l * 8 + e] = (_Float16)v;
        }
    }
}

// ---------------------------------------------------------------------------
// Precompute (MFMA): per wave, 16 x-rows x 256 cols (y:0..127, base:128..255).
// A = fp16(x-row slice), B = wcat from LDS. D layout: col=lane&15,
// row=(lane>>4)*4+i. Outputs stored fp16 (yh, bh); b1 folded into bh.
// ---------------------------------------------------------------------------
__global__ __launch_bounds__(256) void precompute_mfma(
    const float* __restrict__ x, const _Float16* __restrict__ wcat_g,
    const float* __restrict__ b1, _Float16* __restrict__ yh,
    _Float16* __restrict__ bh, int npts)
{
    __shared__ __align__(16) _Float16 wl[16384];   // 32 KiB
    const int tid = threadIdx.x;
    {
        const float4v* src = (const float4v*)wcat_g;
        float4v* dst = (float4v*)wl;
        for (int i = tid; i < 2048; i += 256) dst[i] = src[i];
    }
    __syncthreads();

    const int wave = tid >> 6;
    const int lane = tid & 63;
    const int lrow = lane & 15;
    const int lkg  = lane >> 4;

    const int r0 = blockIdx.x * 64 + wave * 16;
    if (r0 >= npts) return;
    const int arow = (r0 + lrow < npts) ? (r0 + lrow) : (npts - 1);

    // A fragments: lane holds x[arow][ks*32 + lkg*8 + e], ks in {0,1}
    f16x8 a[2];
#pragma unroll
    for (int ks = 0; ks < 2; ++ks) {
        const float* p = x + (size_t)arow * 64 + ks * 32 + lkg * 8;
        float4v u0 = *(const float4v*)p;
        float4v u1 = *(const float4v*)(p + 4);
#pragma unroll
        for (int e = 0; e < 4; ++e) {
            a[ks][e]     = (_Float16)u0[e];
            a[ks][e + 4] = (_Float16)u1[e];
        }
    }

    const f16x8* F = (const f16x8*)wl;
    const int rl = r0 + lkg * 4;          // D rows this lane writes
    const int c = lane & 15;

#pragma unroll
    for (int nt = 0; nt < 16; ++nt) {
        f32x4 acc = {0.f, 0.f, 0.f, 0.f};
        acc = __builtin_amdgcn_mfma_f32_16x16x32_f16(a[0], F[(nt * 2 + 0) * 64 + lane], acc, 0, 0, 0);
        acc = __builtin_amdgcn_mfma_f32_16x16x32_f16(a[1], F[(nt * 2 + 1) * 64 + lane], acc, 0, 0, 0);
        if (nt < 8) {
#pragma unroll
            for (int i = 0; i < 4; ++i)
                if (rl + i < npts)
                    yh[(size_t)(rl + i) * 128 + nt * 16 + c] = (_Float16)acc[i];
        } else {
            const float bb = b1[(nt - 8) * 16 + c];
#pragma unroll
            for (int i = 0; i < 4; ++i)
                if (rl + i < npts)
                    bh[(size_t)(rl + i) * 128 + (nt - 8) * 16 + c] = (_Float16)(acc[i] + bb);
        }
    }
}

// ---------------------------------------------------------------------------
// Main: block = 4 waves, each wave owns one point per grid-stride step.
// Pure-fp16 h = relu(yh[j] + bh[n]); 1-product MFMA vs LDS-resident W2hi
// (32 per point). Next point's loads issued before the MFMA phase (latency
// hidden under compute). NT out stores.
// ---------------------------------------------------------------------------
__global__ __launch_bounds__(256, 4) void edgeconv_main_kernel(
    const _Float16* __restrict__ yh, const _Float16* __restrict__ bh,
    const _Float16* __restrict__ whi_g, const int* __restrict__ ind,
    const float* __restrict__ b2, float* __restrict__ out, int npts)
{
    __shared__ __align__(16) _Float16 wl[16384];   // 32 KiB
    const int tid = threadIdx.x;
    {
        const float4v* src = (const float4v*)whi_g;
        float4v* dst = (float4v*)wl;
        for (int i = tid; i < 2048; i += 256) dst[i] = src[i];
    }
    __syncthreads();

    const int wave = tid >> 6;
    const int lane = tid & 63;
    const int lrow = lane & 15;
    const int lkg  = lane >> 4;

    const f16x8* HI = (const f16x8*)wl;
    const float b2a = b2[lane];
    const float b2b = b2[lane + 64];

    const int stride = gridDim.x * 4;
    int n = blockIdx.x * 4 + wave;       // grid*4 = 4096 <= npts, always valid

    int j = ind[n * 16 + lrow];
    f16x8 yr0, yr1, yr2, yr3, br0, br1, br2, br3;
    {
        const f16x8* yp = (const f16x8*)(yh + (size_t)j * 128 + lkg * 8);
        const f16x8* bp = (const f16x8*)(bh + (size_t)n * 128 + lkg * 8);
        yr0 = yp[0]; yr1 = yp[4]; yr2 = yp[8]; yr3 = yp[12];   // +32 halves = 4 f16x8
        br0 = bp[0]; br1 = bp[4]; br2 = bp[8]; br3 = bp[12];
    }

    for (; n < npts; n += stride) {
        const int n2 = n + stride;
        const int n2c = (n2 < npts) ? n2 : (npts - 1);
        const int j2 = ind[n2c * 16 + lrow];

        // ---- build A fragments (pure fp16) ----
        f16x8 a0 = relu_add(yr0, br0);
        f16x8 a1 = relu_add(yr1, br1);
        f16x8 a2 = relu_add(yr2, br2);
        f16x8 a3 = relu_add(yr3, br3);

        // ---- issue next point's loads (latency hidden by MFMA phase) ----
        {
            const f16x8* yp = (const f16x8*)(yh + (size_t)j2 * 128 + lkg * 8);
            const f16x8* bp = (const f16x8*)(bh + (size_t)n2c * 128 + lkg * 8);
            yr0 = yp[0]; yr1 = yp[4]; yr2 = yp[8]; yr3 = yp[12];
            br0 = bp[0]; br1 = bp[4]; br2 = bp[8]; br3 = bp[12];
        }

        // ---- 8 ntiles x 4 MFMA, max-reduce over the 16 rows ----
        float mv[8];
#pragma unroll
        for (int nt = 0; nt < 8; ++nt) {
            f32x4 acc = {0.f, 0.f, 0.f, 0.f};
            acc = __builtin_amdgcn_mfma_f32_16x16x32_f16(a0, HI[(nt * 4 + 0) * 64 + lane], acc, 0, 0, 0);
            acc = __builtin_amdgcn_mfma_f32_16x16x32_f16(a1, HI[(nt * 4 + 1) * 64 + lane], acc, 0, 0, 0);
            acc = __builtin_amdgcn_mfma_f32_16x16x32_f16(a2, HI[(nt * 4 + 2) * 64 + lane], acc, 0, 0, 0);
            acc = __builtin_amdgcn_mfma_f32_16x16x32_f16(a3, HI[(nt * 4 + 3) * 64 + lane], acc, 0, 0, 0);
            float m = fmaxf(fmaxf(acc[0], acc[1]), fmaxf(acc[2], acc[3]));
            m = fmaxf(m, __shfl_xor(m, 16));
            m = fmaxf(m, __shfl_xor(m, 32));
            mv[nt] = m;
        }

        // ---- store: lane l -> channels l and l+64 ----
        const int g = lkg;
        float mlo = (g == 0) ? mv[0] : (g == 1) ? mv[1] : (g == 2) ? mv[2] : mv[3];
        float mhi = (g == 0) ? mv[4] : (g == 1) ? mv[5] : (g == 2) ? mv[6] : mv[7];
        __builtin_nontemporal_store(mlo + b2a, &out[(size_t)n * 128 + lane]);
        __builtin_nontemporal_store(mhi + b2b, &out[(size_t)n * 128 + 64 + lane]);

        j = j2;
    }
}

// ---------------------------------------------------------------------------
extern "C" void kernel_launch(void* const* d_in, const int* in_sizes, int n_in,
                              void* d_out, int out_size, void* d_ws, size_t ws_size,
                              hipStream_t stream)
{
    const float* x   = (const float*)d_in[0];
    const int*   ind = (const int*)d_in[1];
    const float* W1  = (const float*)d_in[2];
    const float* b1  = (const float*)d_in[3];
    const float* W2  = (const float*)d_in[4];
    const float* b2  = (const float*)d_in[5];
    float* out = (float*)d_out;

    const int npts = in_sizes[0] / 64;           // N = 100000

    // workspace layout
    char* ws = (char*)d_ws;
    _Float16* yh   = (_Float16*)ws;                                  // N*128 f16
    _Float16* bhp  = yh + (size_t)npts * 128;                        // N*128 f16
    _Float16* whi  = bhp + (size_t)npts * 128;                       // 16384 f16
    _Float16* wcat = whi + 16384;                                    // 16384 f16

    hipLaunchKernelGGL(pack_kernel, dim3(64), dim3(64), 0, stream,
                       W1, W2, whi, wcat);
    hipLaunchKernelGGL(precompute_mfma, dim3((npts + 63) / 64), dim3(256), 0, stream,
                       x, wcat, b1, yh, bhp, npts);
    hipLaunchKernelGGL(edgeconv_main_kernel, dim3(1024), dim3(256), 0, stream,
                       yh, bhp, whi, ind, b2, out, npts);
}

// Round 9
// 184.510 us; speedup vs baseline: 2.9888x; 2.2649x over previous
//
#include <hip/hip_runtime.h>
#include <hip/hip_fp16.h>

typedef _Float16 f16x8 __attribute__((ext_vector_type(8)));
typedef float f32x4 __attribute__((ext_vector_type(4)));
typedef float float4v __attribute__((ext_vector_type(4)));

static __device__ __forceinline__ f16x8 relu_add(f16x8 u, f16x8 v) {
    f16x8 s = u + v;
#pragma unroll
    for (int e = 0; e < 8; ++e) s[e] = s[e] > (_Float16)0 ? s[e] : (_Float16)0;
    return s;
}

// ---------------------------------------------------------------------------
// Pack kernel (unchanged): 64 blocks x 64 lanes.
//  blocks 0..31 : W2 -> whi fragments   (fid = nt*4+ks, nt<8, ks<4, K=128)
//  blocks 32..63: W1 -> wcat fragments  (fid = nt*2+ks, nt<16, ks<2, K=64)
// Fragment element (lane l, elem e): B[k0+e][col], col = nt*16+(l&15),
// k0 = ks*32 + (l>>4)*8   (mapping HW-verified rounds 1/3/7)
// ---------------------------------------------------------------------------
__global__ void pack_kernel(const float* __restrict__ W1,
                            const float* __restrict__ W2,
                            _Float16* __restrict__ whi,
                            _Float16* __restrict__ wcat)
{
    const int b = blockIdx.x;
    const int l = threadIdx.x;
    if (b < 32) {
        const int nt = b >> 2, ks = b & 3;
        const int col = nt * 16 + (l & 15);
        const int k0 = ks * 32 + (l >> 4) * 8;
#pragma unroll
        for (int e = 0; e < 8; ++e)
            whi[b * 512 + l * 8 + e] = (_Float16)W2[(k0 + e) * 128 + col];
    } else {
        const int fid = b - 32;
        const int nt = fid >> 1, ks = fid & 1;
        const int col = nt * 16 + (l & 15);
        const int k0 = ks * 32 + (l >> 4) * 8;
#pragma unroll
        for (int e = 0; e < 8; ++e) {
            const int k = k0 + e;
            float v;
            if (col < 128) v = W1[k * 128 + col];
            else           v = W1[(64 + k) * 128 + (col - 128)] - W1[k * 128 + (col - 128)];
            wcat[fid * 512 + l * 8 + e] = (_Float16)v;
        }
    }
}

// ---------------------------------------------------------------------------
// Precompute (MFMA): per wave, 16 x-rows x 256 cols (y:0..127, base:128..255).
// B-frags read directly from global (L2-resident, 32 KiB). Results are
// transposed through a per-wave LDS tile and written with coalesced 16 B
// stores (was: 128 scalar 2 B global stores per wave).
// ---------------------------------------------------------------------------
__global__ __launch_bounds__(256, 3) void precompute_mfma(
    const float* __restrict__ x, const _Float16* __restrict__ wcat_g,
    const float* __restrict__ b1, _Float16* __restrict__ yh,
    _Float16* __restrict__ bh, int npts)
{
    __shared__ __align__(16) _Float16 T[4][16][256];   // 32 KiB

    const int tid  = threadIdx.x;
    const int wave = tid >> 6;
    const int lane = tid & 63;
    const int lrow = lane & 15;
    const int lkg  = lane >> 4;

    const int r0 = blockIdx.x * 64 + wave * 16;
    if (r0 >= npts) return;
    const int arow = (r0 + lrow < npts) ? (r0 + lrow) : (npts - 1);

    // A fragments: lane holds x[arow][ks*32 + lkg*8 + e], ks in {0,1}
    f16x8 a[2];
#pragma unroll
    for (int ks = 0; ks < 2; ++ks) {
        const float* p = x + (size_t)arow * 64 + ks * 32 + lkg * 8;
        float4v u0 = *(const float4v*)p;
        float4v u1 = *(const float4v*)(p + 4);
#pragma unroll
        for (int e = 0; e < 4; ++e) {
            a[ks][e]     = (_Float16)u0[e];
            a[ks][e + 4] = (_Float16)u1[e];
        }
    }

    // bias values for this lane's column across the 8 base-tiles
    float bv[8];
#pragma unroll
    for (int m = 0; m < 8; ++m) bv[m] = b1[m * 16 + lrow];

    const f16x8* F = (const f16x8*)wcat_g;   // direct global B-frags
    const int rloc = lkg * 4;                // local D rows this lane owns

#pragma unroll
    for (int nt = 0; nt < 16; ++nt) {
        f32x4 acc = {0.f, 0.f, 0.f, 0.f};
        acc = __builtin_amdgcn_mfma_f32_16x16x32_f16(a[0], F[(nt * 2 + 0) * 64 + lane], acc, 0, 0, 0);
        acc = __builtin_amdgcn_mfma_f32_16x16x32_f16(a[1], F[(nt * 2 + 1) * 64 + lane], acc, 0, 0, 0);
        if (nt < 8) {
#pragma unroll
            for (int i = 0; i < 4; ++i)
                T[wave][rloc + i][nt * 16 + lrow] = (_Float16)acc[i];
        } else {
#pragma unroll
            for (int i = 0; i < 4; ++i)
                T[wave][rloc + i][128 + (nt - 8) * 16 + lrow] = (_Float16)(acc[i] + bv[nt - 8]);
        }
    }

    // coalesced writeout: 512 chunks of 8 halves; chunk c -> row c>>5, q=c&31
#pragma unroll
    for (int i = 0; i < 8; ++i) {
        const int c = i * 64 + lane;
        const int r = c >> 5;
        const int q = c & 31;
        if (r0 + r < npts) {
            f16x8 v = *(const f16x8*)&T[wave][r][q * 8];
            _Float16* dst = (q < 16)
                ? (yh + (size_t)(r0 + r) * 128 + q * 8)
                : (bh + (size_t)(r0 + r) * 128 + (q - 16) * 8);
            *(f16x8*)dst = v;
        }
    }
}

// ---------------------------------------------------------------------------
// Main: block = 4 waves, each wave owns one point per grid-stride step.
// Gather path: the 16 neighbor y-rows (256 B each) are DMA'd to a per-wave
// LDS buffer with global_load_lds_dwordx4 — each instruction reads 4 full
// rows as whole 128 B lines (kills the 64 B-segment 2x line overfetch).
// A-frags then come from LDS via XOR-swizzled ds_read_b128 (source-
// preswizzled global addresses keep LDS linear; 2-way banks = free).
// bh row + ind stay register-prefetched one step ahead.
// ---------------------------------------------------------------------------
__global__ __launch_bounds__(256, 3) void edgeconv_main_kernel(
    const _Float16* __restrict__ yh, const _Float16* __restrict__ bh,
    const _Float16* __restrict__ whi_g, const int* __restrict__ ind,
    const float* __restrict__ b2, float* __restrict__ out, int npts)
{
    __shared__ __align__(16) _Float16 wl[16384];       // 32 KiB W2 frags
    __shared__ __align__(16) _Float16 stage[4][2048];  // 16 KiB: 4KB/wave

    const int tid = threadIdx.x;
    {   // cooperative 32 KiB W2 copy
        const float4v* src = (const float4v*)whi_g;
        float4v* dst = (float4v*)wl;
        for (int i = tid; i < 2048; i += 256) dst[i] = src[i];
    }
    __syncthreads();

    const int wave = tid >> 6;
    const int lane = tid & 63;
    const int lrow = lane & 15;
    const int lkg  = lane >> 4;

    _Float16* sw = &stage[wave][0];
    const f16x8* HI = (const f16x8*)wl;
    const float b2a = b2[lane];
    const float b2b = b2[lane + 64];

    // DMA 16 y-rows of point with neighbor regs jreg into this wave's buffer.
    // instr i: rows i*4..i*4+3; dest = sw + i*1024B + lane*16B (linear);
    // source chunk pre-swizzled so a ds_read at chunk^(row&7) returns chunk.
    auto stage_point = [&](int jreg) {
#pragma unroll
        for (int i = 0; i < 4; ++i) {
            const int rl = i * 4 + lkg;
            const int js = __shfl(jreg, rl);
            const int gc = lrow ^ (rl & 7);
            const _Float16* g = yh + (size_t)js * 128 + gc * 8;
            __builtin_amdgcn_global_load_lds(
                (const __attribute__((address_space(1))) void*)g,
                (__attribute__((address_space(3))) void*)(sw + i * 512),
                16, 0, 0);
        }
    };

    const int stride = gridDim.x * 4;
    int n = blockIdx.x * 4 + wave;       // grid*4 = 3072 <= npts, always valid
    if (n >= npts) return;

    // ---- prologue: stage point n, prefetch its bh row and next ind ----
    int jcur = ind[n * 16 + lrow];
    stage_point(jcur);
    f16x8 br0, br1, br2, br3;
    {
        const f16x8* bp = (const f16x8*)(bh + (size_t)n * 128 + lkg * 8);
        br0 = bp[0]; br1 = bp[4]; br2 = bp[8]; br3 = bp[12];
    }
    {
        const int nn = n + stride;
        const int nnc = (nn < npts) ? nn : (npts - 1);
        jcur = ind[nnc * 16 + lrow];     // jA for the first loop iteration
    }

    for (; n < npts; n += stride) {
        asm volatile("s_waitcnt vmcnt(0)" ::: "memory");   // staging + prefetches done

        // ---- read staged y-frags (swizzled) and build A ----
        const int rswz = lrow & 7;
        f16x8 yf0 = *(const f16x8*)(sw + lrow * 128 + ((lkg +  0) ^ rswz) * 8);
        f16x8 yf1 = *(const f16x8*)(sw + lrow * 128 + ((lkg +  4) ^ rswz) * 8);
        f16x8 yf2 = *(const f16x8*)(sw + lrow * 128 + ((lkg +  8) ^ rswz) * 8);
        f16x8 yf3 = *(const f16x8*)(sw + lrow * 128 + ((lkg + 12) ^ rswz) * 8);
        f16x8 a0 = relu_add(yf0, br0);
        f16x8 a1 = relu_add(yf1, br1);
        f16x8 a2 = relu_add(yf2, br2);
        f16x8 a3 = relu_add(yf3, br3);

        // ---- issue next point's staging + prefetches (hidden by MFMA) ----
        const int n1 = n + stride;
        const int n1c = (n1 < npts) ? n1 : (npts - 1);
        const int n2 = n + 2 * stride;
        const int n2c = (n2 < npts) ? n2 : (npts - 1);
        stage_point(jcur);                       // DMA for point n1 (a-frags already read)
        const int jB = ind[n2c * 16 + lrow];
        f16x8 c0, c1, c2, c3;
        {
            const f16x8* bp = (const f16x8*)(bh + (size_t)n1c * 128 + lkg * 8);
            c0 = bp[0]; c1 = bp[4]; c2 = bp[8]; c3 = bp[12];
        }

        // ---- 8 ntiles x 4 MFMA, max-reduce over the 16 rows ----
        float mv[8];
#pragma unroll
        for (int nt = 0; nt < 8; ++nt) {
            f32x4 acc = {0.f, 0.f, 0.f, 0.f};
            acc = __builtin_amdgcn_mfma_f32_16x16x32_f16(a0, HI[(nt * 4 + 0) * 64 + lane], acc, 0, 0, 0);
            acc = __builtin_amdgcn_mfma_f32_16x16x32_f16(a1, HI[(nt * 4 + 1) * 64 + lane], acc, 0, 0, 0);
            acc = __builtin_amdgcn_mfma_f32_16x16x32_f16(a2, HI[(nt * 4 + 2) * 64 + lane], acc, 0, 0, 0);
            acc = __builtin_amdgcn_mfma_f32_16x16x32_f16(a3, HI[(nt * 4 + 3) * 64 + lane], acc, 0, 0, 0);
            float m = fmaxf(fmaxf(acc[0], acc[1]), fmaxf(acc[2], acc[3]));
            m = fmaxf(m, __shfl_xor(m, 16));
            m = fmaxf(m, __shfl_xor(m, 32));
            mv[nt] = m;
        }

        // ---- store: lane l -> channels l and l+64 ----
        const int g = lkg;
        float mlo = (g == 0) ? mv[0] : (g == 1) ? mv[1] : (g == 2) ? mv[2] : mv[3];
        float mhi = (g == 0) ? mv[4] : (g == 1) ? mv[5] : (g == 2) ? mv[6] : mv[7];
        __builtin_nontemporal_store(mlo + b2a, &out[(size_t)n * 128 + lane]);
        __builtin_nontemporal_store(mhi + b2b, &out[(size_t)n * 128 + 64 + lane]);

        jcur = jB;
        br0 = c0; br1 = c1; br2 = c2; br3 = c3;
    }
}

// ---------------------------------------------------------------------------
extern "C" void kernel_launch(void* const* d_in, const int* in_sizes, int n_in,
                              void* d_out, int out_size, void* d_ws, size_t ws_size,
                              hipStream_t stream)
{
    const float* x   = (const float*)d_in[0];
    const int*   ind = (const int*)d_in[1];
    const float* W1  = (const float*)d_in[2];
    const float* b1  = (const float*)d_in[3];
    const float* W2  = (const float*)d_in[4];
    const float* b2  = (const float*)d_in[5];
    float* out = (float*)d_out;

    const int npts = in_sizes[0] / 64;           // N = 100000

    // workspace layout
    char* ws = (char*)d_ws;
    _Float16* yh   = (_Float16*)ws;                                  // N*128 f16
    _Float16* bhp  = yh + (size_t)npts * 128;                        // N*128 f16
    _Float16* whi  = bhp + (size_t)npts * 128;                       // 16384 f16
    _Float16* wcat = whi + 16384;                                    // 16384 f16

    hipLaunchKernelGGL(pack_kernel, dim3(64), dim3(64), 0, stream,
                       W1, W2, whi, wcat);
    hipLaunchKernelGGL(precompute_mfma, dim3((npts + 63) / 64), dim3(256), 0, stream,
                       x, wcat, b1, yh, bhp, npts);
    hipLaunchKernelGGL(edgeconv_main_kernel, dim3(768), dim3(256), 0, stream,
                       yh, bhp, whi, ind, b2, out, npts);
}

// Round 13
// 180.921 us; speedup vs baseline: 3.0481x; 1.0198x over previous
//
#include <hip/hip_runtime.h>
#include <hip/hip_fp16.h>

typedef _Float16 f16x8 __attribute__((ext_vector_type(8)));
typedef float f32x4 __attribute__((ext_vector_type(4)));
typedef float float4v __attribute__((ext_vector_type(4)));

static __device__ __forceinline__ f16x8 relu_add(f16x8 u, f16x8 v) {
    f16x8 s = u + v;
#pragma unroll
    for (int e = 0; e < 8; ++e) s[e] = s[e] > (_Float16)0 ? s[e] : (_Float16)0;
    return s;
}

// ---------------------------------------------------------------------------
// Pack kernel (unchanged): 64 blocks x 64 lanes.
//  blocks 0..31 : W2 -> whi fragments   (fid = nt*4+ks, nt<8, ks<4, K=128)
//  blocks 32..63: W1 -> wcat fragments  (fid = nt*2+ks, nt<16, ks<2, K=64)
// Fragment element (lane l, elem e): B[k0+e][col], col = nt*16+(l&15),
// k0 = ks*32 + (l>>4)*8   (mapping HW-verified rounds 1/3/7/9)
// ---------------------------------------------------------------------------
__global__ void pack_kernel(const float* __restrict__ W1,
                            const float* __restrict__ W2,
                            _Float16* __restrict__ whi,
                            _Float16* __restrict__ wcat)
{
    const int b = blockIdx.x;
    const int l = threadIdx.x;
    if (b < 32) {
        const int nt = b >> 2, ks = b & 3;
        const int col = nt * 16 + (l & 15);
        const int k0 = ks * 32 + (l >> 4) * 8;
#pragma unroll
        for (int e = 0; e < 8; ++e)
            whi[b * 512 + l * 8 + e] = (_Float16)W2[(k0 + e) * 128 + col];
    } else {
        const int fid = b - 32;
        const int nt = fid >> 1, ks = fid & 1;
        const int col = nt * 16 + (l & 15);
        const int k0 = ks * 32 + (l >> 4) * 8;
#pragma unroll
        for (int e = 0; e < 8; ++e) {
            const int k = k0 + e;
            float v;
            if (col < 128) v = W1[k * 128 + col];
            else           v = W1[(64 + k) * 128 + (col - 128)] - W1[k * 128 + (col - 128)];
            wcat[fid * 512 + l * 8 + e] = (_Float16)v;
        }
    }
}

// ---------------------------------------------------------------------------
// Precompute (MFMA): per wave, 16 x-rows x 256 cols (y:0..127, base:128..255).
// wcat staged in LDS (short ds_read chain instead of ~250-cyc global-L2
// dependent loads). T transpose tile padded to 264 halves/row: 16-B aligned
// rows, write conflicts reduced from 16-way to <=4-way.
// ---------------------------------------------------------------------------
__global__ __launch_bounds__(256, 2) void precompute_mfma(
    const float* __restrict__ x, const _Float16* __restrict__ wcat_g,
    const float* __restrict__ b1, _Float16* __restrict__ yh,
    _Float16* __restrict__ bh, int npts)
{
    __shared__ __align__(16) _Float16 wl[16384];       // 32 KiB wcat frags
    __shared__ __align__(16) _Float16 T[4][16][264];   // 33 KiB transpose

    const int tid  = threadIdx.x;
    {   // cooperative 32 KiB stage of wcat
        const float4v* src = (const float4v*)wcat_g;
        float4v* dst = (float4v*)wl;
        for (int i = tid; i < 2048; i += 256) dst[i] = src[i];
    }
    __syncthreads();

    const int wave = tid >> 6;
    const int lane = tid & 63;
    const int lrow = lane & 15;
    const int lkg  = lane >> 4;

    const int r0 = blockIdx.x * 64 + wave * 16;
    if (r0 >= npts) return;
    const int arow = (r0 + lrow < npts) ? (r0 + lrow) : (npts - 1);

    // A fragments: lane holds x[arow][ks*32 + lkg*8 + e], ks in {0,1}
    f16x8 a[2];
#pragma unroll
    for (int ks = 0; ks < 2; ++ks) {
        const float* p = x + (size_t)arow * 64 + ks * 32 + lkg * 8;
        float4v u0 = *(const float4v*)p;
        float4v u1 = *(const float4v*)(p + 4);
#pragma unroll
        for (int e = 0; e < 4; ++e) {
            a[ks][e]     = (_Float16)u0[e];
            a[ks][e + 4] = (_Float16)u1[e];
        }
    }

    // bias values for this lane's column across the 8 base-tiles
    float bv[8];
#pragma unroll
    for (int m = 0; m < 8; ++m) bv[m] = b1[m * 16 + lrow];

    const f16x8* F = (const f16x8*)wl;       // LDS-resident B-frags
    const int rloc = lkg * 4;                // local D rows this lane owns

#pragma unroll
    for (int nt = 0; nt < 16; ++nt) {
        f32x4 acc = {0.f, 0.f, 0.f, 0.f};
        acc = __builtin_amdgcn_mfma_f32_16x16x32_f16(a[0], F[(nt * 2 + 0) * 64 + lane], acc, 0, 0, 0);
        acc = __builtin_amdgcn_mfma_f32_16x16x32_f16(a[1], F[(nt * 2 + 1) * 64 + lane], acc, 0, 0, 0);
        if (nt < 8) {
#pragma unroll
            for (int i = 0; i < 4; ++i)
                T[wave][rloc + i][nt * 16 + lrow] = (_Float16)acc[i];
        } else {
#pragma unroll
            for (int i = 0; i < 4; ++i)
                T[wave][rloc + i][128 + (nt - 8) * 16 + lrow] = (_Float16)(acc[i] + bv[nt - 8]);
        }
    }

    // coalesced writeout: 512 chunks of 8 halves; chunk c -> row c>>5, q=c&31
#pragma unroll
    for (int i = 0; i < 8; ++i) {
        const int c = i * 64 + lane;
        const int r = c >> 5;
        const int q = c & 31;
        if (r0 + r < npts) {
            f16x8 v = *(const f16x8*)&T[wave][r][q * 8];
            _Float16* dst = (q < 16)
                ? (yh + (size_t)(r0 + r) * 128 + q * 8)
                : (bh + (size_t)(r0 + r) * 128 + (q - 16) * 8);
            *(f16x8*)dst = v;
        }
    }
}

// ---------------------------------------------------------------------------
// Main: block = 4 waves, each wave owns one point per grid-stride step.
// All 32 W2 B-fragments live in VGPRs (128 regs) — zero per-point W2 LDS
// reads (was 32 KiB of ds_read per point = LDS-issue bound). LDS keeps only
// the 4 KB/wave gather stage (full-line DMA, swizzled ds_read). No barriers.
// bh row + ind register-prefetched one step ahead. NT out stores.
// ---------------------------------------------------------------------------
__global__ __launch_bounds__(256, 2) void edgeconv_main_kernel(
    const _Float16* __restrict__ yh, const _Float16* __restrict__ bh,
    const _Float16* __restrict__ whi_g, const int* __restrict__ ind,
    const float* __restrict__ b2, float* __restrict__ out, int npts)
{
    __shared__ __align__(16) _Float16 stage[4][2048];  // 16 KiB: 4KB/wave

    const int tid = threadIdx.x;
    const int wave = tid >> 6;
    const int lane = tid & 63;
    const int lrow = lane & 15;
    const int lkg  = lane >> 4;

    // ---- W2 fragments into registers (32 x 4 VGPR) ----
    f16x8 B[32];
    {
        const f16x8* src = (const f16x8*)whi_g;
#pragma unroll
        for (int f = 0; f < 32; ++f) B[f] = src[f * 64 + lane];
    }

    _Float16* sw = &stage[wave][0];
    const float b2a = b2[lane];
    const float b2b = b2[lane + 64];

    // DMA 16 y-rows of the point whose neighbor regs are jreg.
    // instr i: rows i*4..i*4+3; dest = sw + i*1024B + lane*16B (linear);
    // source chunk pre-swizzled so a ds_read at chunk^(row&7) returns chunk.
    auto stage_point = [&](int jreg) {
#pragma unroll
        for (int i = 0; i < 4; ++i) {
            const int rl = i * 4 + lkg;
            const int js = __shfl(jreg, rl);
            const int gc = lrow ^ (rl & 7);
            const _Float16* g = yh + (size_t)js * 128 + gc * 8;
            __builtin_amdgcn_global_load_lds(
                (const __attribute__((address_space(1))) void*)g,
                (__attribute__((address_space(3))) void*)(sw + i * 512),
                16, 0, 0);
        }
    };

    const int stride = gridDim.x * 4;
    int n = blockIdx.x * 4 + wave;       // grid*4 = 2048 <= npts, always valid
    if (n >= npts) return;

    // ---- prologue: stage point n, prefetch its bh row and next ind ----
    int jcur = ind[n * 16 + lrow];
    stage_point(jcur);
    f16x8 br0, br1, br2, br3;
    {
        const f16x8* bp = (const f16x8*)(bh + (size_t)n * 128 + lkg * 8);
        br0 = bp[0]; br1 = bp[4]; br2 = bp[8]; br3 = bp[12];
    }
    {
        const int nn = n + stride;
        const int nnc = (nn < npts) ? nn : (npts - 1);
        jcur = ind[nnc * 16 + lrow];     // jA for the first loop iteration
    }

    for (; n < npts; n += stride) {
        asm volatile("s_waitcnt vmcnt(0)" ::: "memory");   // staging + prefetches done

        // ---- read staged y-frags (swizzled) and build A ----
        const int rswz = lrow & 7;
        f16x8 yf0 = *(const f16x8*)(sw + lrow * 128 + ((lkg +  0) ^ rswz) * 8);
        f16x8 yf1 = *(const f16x8*)(sw + lrow * 128 + ((lkg +  4) ^ rswz) * 8);
        f16x8 yf2 = *(const f16x8*)(sw + lrow * 128 + ((lkg +  8) ^ rswz) * 8);
        f16x8 yf3 = *(const f16x8*)(sw + lrow * 128 + ((lkg + 12) ^ rswz) * 8);
        f16x8 a0 = relu_add(yf0, br0);
        f16x8 a1 = relu_add(yf1, br1);
        f16x8 a2 = relu_add(yf2, br2);
        f16x8 a3 = relu_add(yf3, br3);

        // ---- issue next point's staging + prefetches (hidden by MFMA) ----
        const int n1 = n + stride;
        const int n1c = (n1 < npts) ? n1 : (npts - 1);
        const int n2 = n + 2 * stride;
        const int n2c = (n2 < npts) ? n2 : (npts - 1);
        stage_point(jcur);                       // DMA for point n1 (a-frags already read)
        const int jB = ind[n2c * 16 + lrow];
        f16x8 c0, c1, c2, c3;
        {
            const f16x8* bp = (const f16x8*)(bh + (size_t)n1c * 128 + lkg * 8);
            c0 = bp[0]; c1 = bp[4]; c2 = bp[8]; c3 = bp[12];
        }

        // ---- 8 ntiles x 4 MFMA (B in registers), max over the 16 rows ----
        float mv[8];
#pragma unroll
        for (int nt = 0; nt < 8; ++nt) {
            f32x4 acc = {0.f, 0.f, 0.f, 0.f};
            acc = __builtin_amdgcn_mfma_f32_16x16x32_f16(a0, B[nt * 4 + 0], acc, 0, 0, 0);
            acc = __builtin_amdgcn_mfma_f32_16x16x32_f16(a1, B[nt * 4 + 1], acc, 0, 0, 0);
            acc = __builtin_amdgcn_mfma_f32_16x16x32_f16(a2, B[nt * 4 + 2], acc, 0, 0, 0);
            acc = __builtin_amdgcn_mfma_f32_16x16x32_f16(a3, B[nt * 4 + 3], acc, 0, 0, 0);
            float m = fmaxf(fmaxf(acc[0], acc[1]), fmaxf(acc[2], acc[3]));
            m = fmaxf(m, __shfl_xor(m, 16));
            m = fmaxf(m, __shfl_xor(m, 32));
            mv[nt] = m;
        }

        // ---- store: lane l -> channels l and l+64 ----
        const int g = lkg;
        float mlo = (g == 0) ? mv[0] : (g == 1) ? mv[1] : (g == 2) ? mv[2] : mv[3];
        float mhi = (g == 0) ? mv[4] : (g == 1) ? mv[5] : (g == 2) ? mv[6] : mv[7];
        __builtin_nontemporal_store(mlo + b2a, &out[(size_t)n * 128 + lane]);
        __builtin_nontemporal_store(mhi + b2b, &out[(size_t)n * 128 + 64 + lane]);

        jcur = jB;
        br0 = c0; br1 = c1; br2 = c2; br3 = c3;
    }
}

// ---------------------------------------------------------------------------
extern "C" void kernel_launch(void* const* d_in, const int* in_sizes, int n_in,
                              void* d_out, int out_size, void* d_ws, size_t ws_size,
                              hipStream_t stream)
{
    const float* x   = (const float*)d_in[0];
    const int*   ind = (const int*)d_in[1];
    const float* W1  = (const float*)d_in[2];
    const float* b1  = (const float*)d_in[3];
    const float* W2  = (const float*)d_in[4];
    const float* b2  = (const float*)d_in[5];
    float* out = (float*)d_out;

    const int npts = in_sizes[0] / 64;           // N = 100000

    // workspace layout
    char* ws = (char*)d_ws;
    _Float16* yh   = (_Float16*)ws;                                  // N*128 f16
    _Float16* bhp  = yh + (size_t)npts * 128;                        // N*128 f16
    _Float16* whi  = bhp + (size_t)npts * 128;                       // 16384 f16
    _Float16* wcat = whi + 16384;                                    // 16384 f16

    hipLaunchKernelGGL(pack_kernel, dim3(64), dim3(64), 0, stream,
                       W1, W2, whi, wcat);
    hipLaunchKernelGGL(precompute_mfma, dim3((npts + 63) / 64), dim3(256), 0, stream,
                       x, wcat, b1, yh, bhp, npts);
    hipLaunchKernelGGL(edgeconv_main_kernel, dim3(512), dim3(256), 0, stream,
                       yh, bhp, whi, ind, b2, out, npts);
}